// Round 9
// baseline (138.447 us; speedup 1.0000x reference)
//
#include <hip/hip_runtime.h>
#include <hip/hip_cooperative_groups.h>
#include <math.h>

namespace cg = cooperative_groups;

#define BATCH 4
#define NN    12288
#define CIN   3
#define NC    4096
#define NG    12
#define NB    128
#define HSTR  9                  // LDS hist stride: [d][bucket][ch] x 9 floats
#define PSZ   (4 * NB * 8)       // dense partial per block = 4096 floats

// ws float-offsets
#define P_OFF  0                 // partials [192][PSZ]
#define H2_OFF (192 * PSZ)       // scanned hist [NG*4][NB*8]

__launch_bounds__(256)
__global__ void k_coop(const float* __restrict__ spikes,
                       const float* __restrict__ theta,
                       const float* __restrict__ gamma,
                       float* __restrict__ ws,
                       float* __restrict__ out) {
    cg::grid_group grid = cg::this_grid();
    __shared__ float lh[4 * NB * HSTR];          // 18.4 KB
    __shared__ float smn[4], smx[4];
    __shared__ float uScale, uAmin;

    int blk = blockIdx.x, g = blk >> 4, chunk = blk & 15;
    int b = g / CIN, c = g % CIN;
    int tid = threadIdx.x, lane = tid & 63, w = tid >> 6;

    // zero hist (4608 floats)
    #pragma unroll
    for (int q = 0; q < 18; ++q) lh[tid + q * 256] = 0.f;

    // ---- phase A: redundant per-block group stats (coalesced float4 row) ----
    const float4* row = (const float4*)(spikes + b * NN);
    float mn = 1e30f, mx = -1e30f;
    #pragma unroll
    for (int q = 0; q < 12; ++q) {
        int f = tid + q * 256;                   // float4 index < 3072
        float4 v4 = row[f];
        float e[4] = {v4.x, v4.y, v4.z, v4.w};
        int r  = (4 * f) % 3;                    // channel of element j=0
        int j0 = (c - r + 3) % 3;                // first j with channel c
        mn = fminf(mn, e[j0]); mx = fmaxf(mx, e[j0]);
        if (j0 + 3 < 4) { mn = fminf(mn, e[j0 + 3]); mx = fmaxf(mx, e[j0 + 3]); }
    }
    #pragma unroll
    for (int off = 32; off; off >>= 1) {
        mn = fminf(mn, __shfl_down(mn, off));
        mx = fmaxf(mx, __shfl_down(mx, off));
    }
    if (lane == 0) { smn[w] = mn; smx[w] = mx; }
    __syncthreads();                              // also covers lh zeroing
    if (tid == 0) {
        float m0 = fminf(fminf(smn[0], smn[1]), fminf(smn[2], smn[3]));
        float m1 = fmaxf(fmaxf(smx[0], smx[1]), fmaxf(smx[2], smx[3]));
        float scale = 0.25f / fmaxf(m1 - m0, 1e-6f);
        uScale = scale;
        uAmin  = m0 * scale;
    }
    __syncthreads();
    float scale = uScale, amin = uAmin;

    // ---- phase B: own element -> LDS hist -> dense partial ----
    int k = chunk * 256 + tid;
    int v = b * NN + k * CIN + c;
    float a = spikes[v] * scale;
    int bb = (int)((a - amin) * (4.0f * NB));
    bb = bb < 0 ? 0 : (bb > NB - 1 ? NB - 1 : bb);
    float sa, ca; __sincosf(a, &sa, &ca);
    float4 th = ((const float4*)theta)[v];
    float thv[4] = {th.x, th.y, th.z, th.w};
    float sf[4], cf[4], sp[4], cq[4];
    #pragma unroll
    for (int d = 0; d < 4; ++d) {
        float sth, cth; __sincosf(thv[d], &sth, &cth);
        sf[d] = fmaf(cth, sa,  sth * ca);        // sin(th + a)
        cf[d] = fmaf(-sth, sa, cth * ca);        // cos(th + a)
        sp[d] = fmaf(-cth, sa, sth * ca);        // sin(th - a)
        cq[d] = fmaf(sth, sa,  cth * ca);        // cos(th - a)
        float* h = lh + (d * NB + bb) * HSTR;
        atomicAdd(h + 0, sf[d]);      atomicAdd(h + 1, cf[d]);
        atomicAdd(h + 2, a * sf[d]);  atomicAdd(h + 3, a * cf[d]);
        atomicAdd(h + 4, sp[d]);      atomicAdd(h + 5, cq[d]);
        atomicAdd(h + 6, a * sp[d]);  atomicAdd(h + 7, a * cq[d]);
    }
    __syncthreads();

    float* P = ws + P_OFF + (size_t)blk * PSZ;
    #pragma unroll
    for (int q = 0; q < 16; ++q) {
        int o = tid + q * 256;                   // (d*NB+bb)*8 + ch
        P[o] = lh[(o >> 3) * HSTR + (o & 7)];
    }

    grid.sync();

    // ---- phase C: blocks 0..47 = (g,d): merge 16 partials once + scan ----
    if (blk < 48) {
        int gg = blk >> 2, d = blk & 3;
        const float* Pg = ws + P_OFF + (size_t)(gg * 16) * PSZ + d * NB * 8;
        #pragma unroll
        for (int q = 0; q < 4; ++q) {
            int o = tid + q * 256;               // < 1024
            float s = 0.f;
            #pragma unroll
            for (int p = 0; p < 16; ++p) s += Pg[(size_t)p * PSZ + o];
            lh[(o >> 3) * HSTR + (o & 7)] = s;
        }
        __syncthreads();
        #pragma unroll
        for (int p = 0; p < 2; ++p) {
            int ch = w * 2 + p;
            float x0 = lh[(lane * 2 + 0) * HSTR + ch];
            float x1 = lh[(lane * 2 + 1) * HSTR + ch];
            float i0 = x0, i1 = i0 + x1;
            float incl = i1;
            #pragma unroll
            for (int off = 1; off < 64; off <<= 1) {
                float o = __shfl_up(incl, off);
                if (lane >= off) incl += o;
            }
            float ebt = incl - i1;
            lh[(lane * 2 + 0) * HSTR + ch] = ebt + i0;
            lh[(lane * 2 + 1) * HSTR + ch] = ebt + i1;
        }
        __syncthreads();
        float* H2 = ws + H2_OFF + (size_t)blk * (NB * 8);
        #pragma unroll
        for (int q = 0; q < 4; ++q) {
            int o = tid + q * 256;
            H2[o] = lh[(o >> 3) * HSTR + (o & 7)];
        }
    }

    grid.sync();

    // ---- phase D: combine (registers carried from B) + gamma + normalize ----
    float4 gm = ((const float4*)gamma)[v];
    float cp[4];
    #pragma unroll
    for (int d = 0; d < 4; ++d) {
        const float4* H4 = (const float4*)(ws + H2_OFF + (size_t)(g * 4 + d) * (NB * 8));
        float4 Plo = H4[bb * 2];
        float4 Phi = H4[bb * 2 + 1];
        float4 T   = H4[(NB - 1) * 2 + 1];
        float lowS = fmaf(0.25f - a, Plo.x, Plo.z);
        float lowC = fmaf(0.25f - a, Plo.y, Plo.w);
        float lower = cf[d] * lowS - sf[d] * lowC;
        float S4 = T.x - Phi.x, S5 = T.y - Phi.y;
        float S6 = T.z - Phi.z, S7 = T.w - Phi.w;
        float upS = fmaf(0.25f + a, S4, -S6);
        float upC = fmaf(0.25f + a, S5, -S7);
        float upper = cq[d] * upS - sp[d] * upC;
        cp[d] = (lower + upper) * (1.0f / (float)NC);
    }
    float tx = gm.x + cp[0], ty = gm.y + cp[1];
    float tz = gm.z + cp[2], tw = gm.w + cp[3];
    float nrm = sqrtf(tx * tx + ty * ty + tz * tz + tw * tw);
    float inv = 1.0f / fmaxf(nrm, 1e-6f);
    ((float4*)out)[v] = make_float4(tx * inv, ty * inv, tz * inv, tw * inv);
}

extern "C" void kernel_launch(void* const* d_in, const int* in_sizes, int n_in,
                              void* d_out, int out_size, void* d_ws, size_t ws_size,
                              hipStream_t stream) {
    const float* theta  = (const float*)d_in[0];
    const float* gamma  = (const float*)d_in[1];
    const float* spikes = (const float*)d_in[2];
    float* out = (float*)d_out;
    float* ws  = (float*)d_ws;

    void* args[] = {(void*)&spikes, (void*)&theta, (void*)&gamma,
                    (void*)&ws, (void*)&out};
    hipLaunchCooperativeKernel((void*)k_coop, dim3(NG * 16), dim3(256),
                               args, 0, stream);
}

// Round 10
// 79.881 us; speedup vs baseline: 1.7332x; 1.7332x over previous
//
#include <hip/hip_runtime.h>
#include <math.h>

#define BATCH 4
#define NN    12288
#define CIN   3
#define NC    4096
#define NG    12
#define NB    128
#define HSTR  9                  // LDS hist stride: [d][bucket][ch] x 9 floats
#define PSZ   (4 * NB * 8)       // dense partial per hist-block = 4096 floats

// ws float-offsets
#define SC_OFF 0                             // per group: scale, amin [NG*2]
#define P_OFF  64                            // partials [192][PSZ]
#define H2_OFF (P_OFF + 192 * PSZ)           // scanned hist [NG*4][NB*8]

// ---------- kernel 1: fused stats (redundant, coalesced) + own-chunk hist ----
__launch_bounds__(256)
__global__ void k_hist(const float* __restrict__ spikes,
                       const float* __restrict__ theta,
                       float* __restrict__ ws) {
    __shared__ float lh[4 * NB * HSTR];       // 4608 floats = 18 KB
    __shared__ float smn[4], smx[4];
    __shared__ float uScale, uAmin;

    int blk = blockIdx.x, g = blk >> 4, chunk = blk & 15;
    int b = g / CIN, c = g % CIN;
    int tid = threadIdx.x, lane = tid & 63, w = tid >> 6;

    #pragma unroll
    for (int q = 0; q < 18; ++q) lh[tid + q * 256] = 0.f;

    // group min/max from the coalesced float4 row (L2-hot across blocks)
    const float4* row = (const float4*)(spikes + b * NN);
    float mn = 1e30f, mx = -1e30f;
    #pragma unroll
    for (int q = 0; q < 12; ++q) {
        int f = tid + q * 256;                // float4 index < 3072
        float4 v4 = row[f];
        float e[4] = {v4.x, v4.y, v4.z, v4.w};
        int r  = (4 * f) % 3;                 // channel of element j=0
        int j0 = (c - r + 3) % 3;             // first j with channel c
        mn = fminf(mn, e[j0]); mx = fmaxf(mx, e[j0]);
        if (j0 + 3 < 4) { mn = fminf(mn, e[j0 + 3]); mx = fmaxf(mx, e[j0 + 3]); }
    }
    #pragma unroll
    for (int off = 32; off; off >>= 1) {
        mn = fminf(mn, __shfl_down(mn, off));
        mx = fmaxf(mx, __shfl_down(mx, off));
    }
    if (lane == 0) { smn[w] = mn; smx[w] = mx; }
    __syncthreads();                           // also covers lh zeroing
    if (tid == 0) {
        float m0 = fminf(fminf(smn[0], smn[1]), fminf(smn[2], smn[3]));
        float m1 = fmaxf(fmaxf(smx[0], smx[1]), fmaxf(smx[2], smx[3]));
        float scale = 0.25f / fmaxf(m1 - m0, 1e-6f);
        uScale = scale;
        uAmin  = m0 * scale;
    }
    __syncthreads();
    float scale = uScale, amin = uAmin;

    // own element -> 4 dims x 8 channels into LDS hist
    int k = chunk * 256 + tid;
    int v = b * NN + k * CIN + c;
    float a = spikes[v] * scale;
    int bb = (int)((a - amin) * (4.0f * NB));
    bb = bb < 0 ? 0 : (bb > NB - 1 ? NB - 1 : bb);
    float sa, ca; __sincosf(a, &sa, &ca);
    float4 th = ((const float4*)theta)[v];
    float thv[4] = {th.x, th.y, th.z, th.w};
    #pragma unroll
    for (int d = 0; d < 4; ++d) {
        float sth, cth; __sincosf(thv[d], &sth, &cth);
        float sf = fmaf(cth, sa,  sth * ca);   // sin(th + a)
        float cf = fmaf(-sth, sa, cth * ca);   // cos(th + a)
        float sp = fmaf(-cth, sa, sth * ca);   // sin(th - a)
        float cq = fmaf(sth, sa,  cth * ca);   // cos(th - a)
        float* h = lh + (d * NB + bb) * HSTR;
        atomicAdd(h + 0, sf);      atomicAdd(h + 1, cf);
        atomicAdd(h + 2, a * sf);  atomicAdd(h + 3, a * cf);
        atomicAdd(h + 4, sp);      atomicAdd(h + 5, cq);
        atomicAdd(h + 6, a * sp);  atomicAdd(h + 7, a * cq);
    }
    __syncthreads();

    float* P = ws + P_OFF + (size_t)blk * PSZ;
    #pragma unroll
    for (int q = 0; q < 16; ++q) {
        int o = tid + q * 256;                 // (d*NB+bb)*8 + ch
        P[o] = lh[(o >> 3) * HSTR + (o & 7)];
    }
    if (chunk == 0 && tid == 0) {
        ws[SC_OFF + g * 2]     = scale;
        ws[SC_OFF + g * 2 + 1] = amin;
    }
}

// ---------- kernel 2: per (g,d): merge 16 partials once + scan -> H2 -------
__launch_bounds__(256)
__global__ void k_mscan(float* __restrict__ ws) {
    __shared__ float lh[NB * HSTR];            // 1152 floats
    int gd = blockIdx.x, g = gd >> 2, d = gd & 3;
    int tid = threadIdx.x, lane = tid & 63, w = tid >> 6;

    const float* Pg = ws + P_OFF + (size_t)(g * 16) * PSZ + d * NB * 8;
    #pragma unroll
    for (int q = 0; q < 4; ++q) {
        int o = tid + q * 256;                 // < 1024 = NB*8
        float s = 0.f;
        #pragma unroll
        for (int p = 0; p < 16; ++p) s += Pg[(size_t)p * PSZ + o];
        lh[(o >> 3) * HSTR + (o & 7)] = s;
    }
    __syncthreads();

    // inclusive scan over 128 buckets; 4 waves x 2 channels, 2 buckets/lane
    #pragma unroll
    for (int p = 0; p < 2; ++p) {
        int ch = w * 2 + p;
        float x0 = lh[(lane * 2 + 0) * HSTR + ch];
        float x1 = lh[(lane * 2 + 1) * HSTR + ch];
        float i0 = x0, i1 = i0 + x1;
        float incl = i1;
        #pragma unroll
        for (int off = 1; off < 64; off <<= 1) {
            float o = __shfl_up(incl, off);
            if (lane >= off) incl += o;
        }
        float ebt = incl - i1;
        lh[(lane * 2 + 0) * HSTR + ch] = ebt + i0;
        lh[(lane * 2 + 1) * HSTR + ch] = ebt + i1;
    }
    __syncthreads();

    float* H2 = ws + H2_OFF + (size_t)gd * (NB * 8);
    #pragma unroll
    for (int q = 0; q < 4; ++q) {
        int o = tid + q * 256;
        H2[o] = lh[(o >> 3) * HSTR + (o & 7)];
    }
}

// ---------- kernel 3: per-node combine + gamma + normalize -----------------
__launch_bounds__(256)
__global__ void k_apply(const float* __restrict__ spikes,
                        const float* __restrict__ theta,
                        const float* __restrict__ gamma,
                        const float* __restrict__ ws,
                        float* __restrict__ out) {
    int blk = blockIdx.x, g = blk >> 4, chunk = blk & 15;
    int b = g / CIN, c = g % CIN;
    int tid = threadIdx.x;
    float scale = ws[SC_OFF + g * 2], amin = ws[SC_OFF + g * 2 + 1];
    int k = chunk * 256 + tid;
    int v = b * NN + k * CIN + c;
    float a = spikes[v] * scale;
    int bb = (int)((a - amin) * (4.0f * NB));
    bb = bb < 0 ? 0 : (bb > NB - 1 ? NB - 1 : bb);
    float sa, ca; __sincosf(a, &sa, &ca);
    float4 th = ((const float4*)theta)[v];
    float4 gm = ((const float4*)gamma)[v];
    float thv[4] = {th.x, th.y, th.z, th.w};
    float cp[4];
    #pragma unroll
    for (int d = 0; d < 4; ++d) {
        float sth, cth; __sincosf(thv[d], &sth, &cth);
        float sf = fmaf(cth, sa,  sth * ca);
        float cf = fmaf(-sth, sa, cth * ca);
        float sp = fmaf(-cth, sa, sth * ca);
        float cq = fmaf(sth, sa,  cth * ca);
        const float4* H4 = (const float4*)(ws + H2_OFF + (size_t)(g * 4 + d) * (NB * 8));
        float4 Plo = H4[bb * 2];
        float4 Phi = H4[bb * 2 + 1];
        float4 T   = H4[(NB - 1) * 2 + 1];
        float lowS = fmaf(0.25f - a, Plo.x, Plo.z);
        float lowC = fmaf(0.25f - a, Plo.y, Plo.w);
        float lower = cf * lowS - sf * lowC;
        float S4 = T.x - Phi.x, S5 = T.y - Phi.y;
        float S6 = T.z - Phi.z, S7 = T.w - Phi.w;
        float upS = fmaf(0.25f + a, S4, -S6);
        float upC = fmaf(0.25f + a, S5, -S7);
        float upper = cq * upS - sp * upC;
        cp[d] = (lower + upper) * (1.0f / (float)NC);
    }
    float tx = gm.x + cp[0], ty = gm.y + cp[1];
    float tz = gm.z + cp[2], tw = gm.w + cp[3];
    float nrm = sqrtf(tx * tx + ty * ty + tz * tz + tw * tw);
    float inv = 1.0f / fmaxf(nrm, 1e-6f);
    ((float4*)out)[v] = make_float4(tx * inv, ty * inv, tz * inv, tw * inv);
}

extern "C" void kernel_launch(void* const* d_in, const int* in_sizes, int n_in,
                              void* d_out, int out_size, void* d_ws, size_t ws_size,
                              hipStream_t stream) {
    const float* theta  = (const float*)d_in[0];
    const float* gamma  = (const float*)d_in[1];
    const float* spikes = (const float*)d_in[2];
    float* out = (float*)d_out;
    float* ws  = (float*)d_ws;

    hipLaunchKernelGGL(k_hist,  dim3(NG * 16), dim3(256), 0, stream, spikes, theta, ws);
    hipLaunchKernelGGL(k_mscan, dim3(NG * 4),  dim3(256), 0, stream, ws);
    hipLaunchKernelGGL(k_apply, dim3(NG * 16), dim3(256), 0, stream,
                       spikes, theta, gamma, ws, out);
}

// Round 11
// 70.889 us; speedup vs baseline: 1.9530x; 1.1269x over previous
//
#include <hip/hip_runtime.h>
#include <math.h>

#define BATCH 4
#define NN    12288
#define CIN   3
#define NC    4096
#define NG    12
#define NB    128
#define HS3   3                    // k_hist LDS stride: 2 ch + 1 pad (banks spread)
#define PSZ   (4 * NB * 2)         // dense partial per hist block = 1024 floats
#define HSTR  9                    // k_mscan 8-channel scan stride

// ws float-offsets
#define SC_OFF 0                             // per group: scale, amin [NG*2]
#define P_OFF  64                            // partials [192][PSZ]
#define H2_OFF (P_OFF + 192 * PSZ)           // scanned hist [NG*4][NB*8]

// ---------- kernel 1: fused stats + own-chunk 2-channel hist ----------------
__launch_bounds__(256)
__global__ void k_hist(const float* __restrict__ spikes,
                       const float* __restrict__ theta,
                       float* __restrict__ ws) {
    __shared__ float lh[4 * NB * HS3];        // 1536 floats
    __shared__ float smn[4], smx[4];
    __shared__ float uScale, uAmin;

    int blk = blockIdx.x, g = blk >> 4, chunk = blk & 15;
    int b = g / CIN, c = g % CIN;
    int tid = threadIdx.x, lane = tid & 63, w = tid >> 6;

    #pragma unroll
    for (int q = 0; q < 6; ++q) lh[tid + q * 256] = 0.f;

    // group min/max from the coalesced float4 row (L2-hot across blocks)
    const float4* row = (const float4*)(spikes + b * NN);
    float mn = 1e30f, mx = -1e30f;
    #pragma unroll
    for (int q = 0; q < 12; ++q) {
        int f = tid + q * 256;                // float4 index < 3072
        float4 v4 = row[f];
        float e[4] = {v4.x, v4.y, v4.z, v4.w};
        int r  = (4 * f) % 3;                 // channel of element j=0
        int j0 = (c - r + 3) % 3;             // first j with channel c
        mn = fminf(mn, e[j0]); mx = fmaxf(mx, e[j0]);
        if (j0 + 3 < 4) { mn = fminf(mn, e[j0 + 3]); mx = fmaxf(mx, e[j0 + 3]); }
    }
    #pragma unroll
    for (int off = 32; off; off >>= 1) {
        mn = fminf(mn, __shfl_down(mn, off));
        mx = fmaxf(mx, __shfl_down(mx, off));
    }
    if (lane == 0) { smn[w] = mn; smx[w] = mx; }
    __syncthreads();                           // also covers lh zeroing
    if (tid == 0) {
        float m0 = fminf(fminf(smn[0], smn[1]), fminf(smn[2], smn[3]));
        float m1 = fmaxf(fmaxf(smx[0], smx[1]), fmaxf(smx[2], smx[3]));
        float scale = 0.25f / fmaxf(m1 - m0, 1e-6f);
        uScale = scale;
        uAmin  = m0 * scale;
    }
    __syncthreads();
    float scale = uScale, amin = uAmin;

    // own element -> 4 dims x 2 channels (8 atomics)
    int k = chunk * 256 + tid;
    int v = b * NN + k * CIN + c;
    float a = spikes[v] * scale;
    int bb = (int)((a - amin) * (4.0f * NB));
    bb = bb < 0 ? 0 : (bb > NB - 1 ? NB - 1 : bb);
    float4 th = ((const float4*)theta)[v];
    float thv[4] = {th.x, th.y, th.z, th.w};
    #pragma unroll
    for (int d = 0; d < 4; ++d) {
        float sth, cth; __sincosf(thv[d], &sth, &cth);
        float* h = lh + (d * NB + bb) * HS3;
        atomicAdd(h + 0, sth);
        atomicAdd(h + 1, cth);
    }
    __syncthreads();

    float* P = ws + P_OFF + (size_t)blk * PSZ;
    #pragma unroll
    for (int q = 0; q < 4; ++q) {
        int o = tid + q * 256;                 // (d*NB+bb)*2 + ch
        P[o] = lh[(o >> 1) * HS3 + (o & 1)];
    }
    if (chunk == 0 && tid == 0) {
        ws[SC_OFF + g * 2]     = scale;
        ws[SC_OFF + g * 2 + 1] = amin;
    }
}

// ---------- kernel 2: per (g,d): merge partials, derive 8 ch, scan -> H2 ----
__launch_bounds__(256)
__global__ void k_mscan(float* __restrict__ ws) {
    __shared__ float raw[256];                 // merged (bb*2+ch)
    __shared__ float lh[NB * HSTR];            // derived 8-channel
    int gd = blockIdx.x, g = gd >> 2, d = gd & 3;
    int tid = threadIdx.x, lane = tid & 63, w = tid >> 6;

    const float* Pg = ws + P_OFF + (size_t)(g * 16) * PSZ + d * (NB * 2);
    float s = 0.f;
    #pragma unroll
    for (int p = 0; p < 16; ++p) s += Pg[(size_t)p * PSZ + tid];
    raw[tid] = s;
    __syncthreads();

    float amin = ws[SC_OFF + g * 2 + 1];
    if (tid < NB) {
        float Ss = raw[tid * 2], Sc = raw[tid * 2 + 1];
        float abar = amin + ((float)tid + 0.5f) * (0.25f / (float)NB);
        float sa, ca; __sincosf(abar, &sa, &ca);
        float c0 = fmaf(ca, Ss,  sa * Sc);     // ~ sum sin(th + a)
        float c1 = fmaf(ca, Sc, -sa * Ss);     // ~ sum cos(th + a)
        float c4 = fmaf(ca, Ss, -sa * Sc);     // ~ sum sin(th - a)
        float c5 = fmaf(ca, Sc,  sa * Ss);     // ~ sum cos(th - a)
        float* L = lh + tid * HSTR;
        L[0] = c0;        L[1] = c1;
        L[2] = abar * c0; L[3] = abar * c1;
        L[4] = c4;        L[5] = c5;
        L[6] = abar * c4; L[7] = abar * c5;
    }
    __syncthreads();

    // inclusive scan over 128 buckets; 4 waves x 2 channels, 2 buckets/lane
    #pragma unroll
    for (int p = 0; p < 2; ++p) {
        int ch = w * 2 + p;
        float x0 = lh[(lane * 2 + 0) * HSTR + ch];
        float x1 = lh[(lane * 2 + 1) * HSTR + ch];
        float i0 = x0, i1 = i0 + x1;
        float incl = i1;
        #pragma unroll
        for (int off = 1; off < 64; off <<= 1) {
            float o = __shfl_up(incl, off);
            if (lane >= off) incl += o;
        }
        float ebt = incl - i1;
        lh[(lane * 2 + 0) * HSTR + ch] = ebt + i0;
        lh[(lane * 2 + 1) * HSTR + ch] = ebt + i1;
    }
    __syncthreads();

    float* H2 = ws + H2_OFF + (size_t)gd * (NB * 8);
    #pragma unroll
    for (int q = 0; q < 4; ++q) {
        int o = tid + q * 256;
        H2[o] = lh[(o >> 3) * HSTR + (o & 7)];
    }
}

// ---------- kernel 3: contiguous nodes, LDS-staged H2, fused epilogue ------
__launch_bounds__(256)
__global__ void k_apply(const float* __restrict__ spikes,
                        const float* __restrict__ theta,
                        const float* __restrict__ gamma,
                        const float* __restrict__ ws,
                        float* __restrict__ out) {
    __shared__ __align__(16) float lH[CIN * 4 * NB * 8];   // 48 KB: batch's 12 gd-slices
    int v = blockIdx.x * 256 + threadIdx.x;    // node, < BATCH*NN (blocks don't straddle b)
    int b = v / NN;

    // stage this batch's scanned histograms (coalesced float4)
    const float4* src = (const float4*)(ws + H2_OFF + (size_t)b * (CIN * 4 * NB * 8));
    float4* dst = (float4*)lH;
    #pragma unroll
    for (int q = 0; q < 12; ++q) {
        int i = threadIdx.x + q * 256;         // < 3072
        dst[i] = src[i];
    }
    __syncthreads();

    int r = v - b * NN;
    int c = r % 3;
    int g = b * CIN + c;
    float scale = ws[SC_OFF + g * 2], amin = ws[SC_OFF + g * 2 + 1];
    float a = spikes[v] * scale;
    int bb = (int)((a - amin) * (4.0f * NB));
    bb = bb < 0 ? 0 : (bb > NB - 1 ? NB - 1 : bb);
    float sa, ca; __sincosf(a, &sa, &ca);
    float4 th = ((const float4*)theta)[v];
    float4 gm = ((const float4*)gamma)[v];
    float thv[4] = {th.x, th.y, th.z, th.w};
    float cp[4];
    #pragma unroll
    for (int d = 0; d < 4; ++d) {
        float sth, cth; __sincosf(thv[d], &sth, &cth);
        float sf = fmaf(cth, sa,  sth * ca);   // sin(th + a), exact i-side
        float cf = fmaf(-sth, sa, cth * ca);   // cos(th + a)
        float sp = fmaf(-cth, sa, sth * ca);   // sin(th - a)
        float cq = fmaf(sth, sa,  cth * ca);   // cos(th - a)
        const float4* Hq = (const float4*)(lH + (c * 4 + d) * (NB * 8));
        float4 Plo = Hq[bb * 2];
        float4 Phi = Hq[bb * 2 + 1];
        float4 T   = Hq[(NB - 1) * 2 + 1];
        float lowS = fmaf(0.25f - a, Plo.x, Plo.z);
        float lowC = fmaf(0.25f - a, Plo.y, Plo.w);
        float lower = cf * lowS - sf * lowC;
        float S4 = T.x - Phi.x, S5 = T.y - Phi.y;
        float S6 = T.z - Phi.z, S7 = T.w - Phi.w;
        float upS = fmaf(0.25f + a, S4, -S6);
        float upC = fmaf(0.25f + a, S5, -S7);
        float upper = cq * upS - sp * upC;
        cp[d] = (lower + upper) * (1.0f / (float)NC);
    }
    float tx = gm.x + cp[0], ty = gm.y + cp[1];
    float tz = gm.z + cp[2], tw = gm.w + cp[3];
    float nrm = sqrtf(tx * tx + ty * ty + tz * tz + tw * tw);
    float inv = 1.0f / fmaxf(nrm, 1e-6f);
    ((float4*)out)[v] = make_float4(tx * inv, ty * inv, tz * inv, tw * inv);
}

extern "C" void kernel_launch(void* const* d_in, const int* in_sizes, int n_in,
                              void* d_out, int out_size, void* d_ws, size_t ws_size,
                              hipStream_t stream) {
    const float* theta  = (const float*)d_in[0];
    const float* gamma  = (const float*)d_in[1];
    const float* spikes = (const float*)d_in[2];
    float* out = (float*)d_out;
    float* ws  = (float*)d_ws;

    hipLaunchKernelGGL(k_hist,  dim3(NG * 16),       dim3(256), 0, stream, spikes, theta, ws);
    hipLaunchKernelGGL(k_mscan, dim3(NG * 4),        dim3(256), 0, stream, ws);
    hipLaunchKernelGGL(k_apply, dim3(BATCH*NN/256),  dim3(256), 0, stream,
                       spikes, theta, gamma, ws, out);
}